// Round 10
// baseline (52.202 us; speedup 1.0000x reference)
//
#include <hip/hip_runtime.h>

#define H 200
#define NP 64
#define NIMG 24
#define NB 8
#define NPIX (H*H)
#define GSTEP (2.0f/199.0f)
#define SPI 20            // strip-halves per image (10 y-strips of 20 rows x 2 x-halves)
#define NWORK (NIMG*SPI)  // 480 blocks; LDS 46KB -> 3 blocks/CU -> capacity 768 >= 480

typedef __fp16 h2 __attribute__((ext_vector_type(2)));

__device__ __forceinline__ float fdot2f(unsigned int a, unsigned int b, float c) {
  h2 ha = __builtin_bit_cast(h2, a);
  h2 hb = __builtin_bit_cast(h2, b);
#if __has_builtin(__builtin_amdgcn_fdot2)
  return __builtin_amdgcn_fdot2(ha, hb, c, false);
#else
  return c + (float)ha.x * (float)hb.x + (float)ha.y * (float)hb.y;
#endif
}

__device__ __forceinline__ unsigned int pk2(float lo, float hi) {
#if __has_builtin(__builtin_amdgcn_cvt_pkrtz)
  h2 h = __builtin_amdgcn_cvt_pkrtz(lo, hi);
  return __builtin_bit_cast(unsigned int, h);
#else
  h2 h; h.x = (__fp16)lo; h.y = (__fp16)hi;
  return __builtin_bit_cast(unsigned int, h);
#endif
}

__device__ __forceinline__ float agentLoadF(const float* p) {
  return __hip_atomic_load(p, __ATOMIC_RELAXED, __HIP_MEMORY_SCOPE_AGENT);
}
__device__ __forceinline__ unsigned int agentLoadU(const unsigned int* p) {
  return __hip_atomic_load(p, __ATOMIC_RELAXED, __HIP_MEMORY_SCOPE_AGENT);
}

// Single kernel. One block per (img, 20-row y-strip, 100-col x-half).
// Phases A/B = R7's verified math (mask GEMM f32, score GEMM f16 y-pair dot2).
// Then per-image (20-block) and per-batch (60-block) atomic counter sync;
// normalized mask written once from registers; 8 blocks finalize scores.
__global__ __launch_bounds__(256, 3) void prs_all(
    const float* __restrict__ cam,   // (8,3,2,3)
    const float* __restrict__ cloud, // (8,64,3)
    const float* __restrict__ mt,    // (8,3,200,200)
    const float* __restrict__ blur,  // (8,64)
    const float* __restrict__ b3,    // (8,3)
    const float* __restrict__ b2,    // (8,3,2)
    float* __restrict__ out,
    unsigned int* __restrict__ cnt,  // [1024] u32: img at i*16, bat at 512+b*16
    float* __restrict__ ws_msum,     // [512]
    float* __restrict__ ws_scr)      // [NWORK][64]
{
  __shared__ float ex[NP*100];          // [n][x] f32        25600 B
  __shared__ float eys[20*NP];          // [y][n] f32         5120 B
  __shared__ float eyt[NP*20];          // [n][y] f32         5120 B
  __shared__ unsigned int eyy[NP*12];   // [n][y2] f16-pair   3072 B (10 used)
  __shared__ unsigned int Mp[100*12];   // [x][y2] f16-pair   4800 B (10 used)
  __shared__ float cinv[100];
  __shared__ float Sy[NP];
  __shared__ float ptx[NP], pty[NP], i2s[NP];
  __shared__ float red[256];

  const int tid = threadIdx.x;
  const int blk = blockIdx.x;
  const int img = blk / SPI;
  const int rem = blk - img * SPI;
  const int strip = rem >> 1;
  const int xh = rem & 1;
  const int b = img / 3;
  const int c = img - 3 * b;
  const int bat = img / 3;
  const int ys0 = strip * 20;
  const int xb = xh * 100;

  // ---- A1: point params ----
  if (tid < NP) {
    int n = tid;
    float p0 = cloud[(b*NP + n)*3 + 0] + b3[b*3 + 0];
    float p1 = cloud[(b*NP + n)*3 + 1] + b3[b*3 + 1];
    float p2 = cloud[(b*NP + n)*3 + 2] + b3[b*3 + 2];
    const float* cc = cam + ((b*3 + c)*2)*3;
    float px = cc[0]*p0 + cc[1]*p1 + cc[2]*p2 - b2[(b*3 + c)*2 + 0];
    float py = cc[3]*p0 + cc[4]*p1 + cc[5]*p2 - b2[(b*3 + c)*2 + 1];
    ptx[n] = fminf(fmaxf(px * 0.01f, -1.0f), 1.0f);
    pty[n] = fminf(fmaxf(py * 0.01f, -1.0f), 1.0f);
    float s = blur[b*NP + n];
    i2s[n] = 1.0f / (2.0f * s * s);
  }
  __syncthreads();

  // ---- A2: eys (strip), ex (x-half), Syp (full-y, into red) ----
  for (int e = tid; e < 20*NP; e += 256) {
    int y = e >> 6, n = e & 63;
    float d = (-1.0f + (ys0 + y)*GSTEP) - pty[n];
    eys[y*NP + n] = __expf(-d*d*i2s[n]);
  }
  for (int e = tid; e < NP*100; e += 256) {
    int n = e / 100, x = e - n*100;
    float d = (-1.0f + (xb + x)*GSTEP) - ptx[n];
    ex[n*100 + x] = __expf(-d*d*i2s[n]);
  }
  {
    int n = tid & 63, g = tid >> 6;
    float pyv = pty[n], iv = i2s[n];
    float s = 0.0f;
    for (int y = g*50; y < g*50 + 50; ++y) {
      float d = (-1.0f + y*GSTEP) - pyv;
      s += __expf(-d*d*iv);
    }
    red[g*NP + n] = s;
  }
  __syncthreads();

  // ---- A3: transpose + f16 packs + M staging + Sy reduce ----
  for (int e = tid; e < NP*20; e += 256) {          // eyt[n][y]
    int n = e / 20, y = e - n*20;
    eyt[n*20 + y] = eys[y*NP + n];
  }
  for (int e = tid; e < 640; e += 256) {            // eyy[n][y2]
    int n = e / 10, y2 = e - n*10;
    eyy[n*12 + y2] = pk2(eys[(2*y2)*NP + n], eys[(2*y2+1)*NP + n]);
  }
  for (int e = tid; e < 1000; e += 256) {           // Mp[x][y2]
    int y2 = e / 100, x = e - y2*100;
    const float* mb = mt + img*NPIX + (ys0 + 2*y2)*H + xb + x;
    Mp[x*12 + y2] = pk2(mb[0], mb[H]);
  }
  if (tid < NP)
    Sy[tid] = red[tid] + red[NP + tid] + red[2*NP + tid] + red[3*NP + tid];
  __syncthreads();

  // ---- A4: cinv (all f32) ----
  if (tid < 100) {
    float s = 0.0f;
    for (int n = 0; n < NP; ++n) s += ex[n*100 + tid] * Sy[n];
    cinv[tid] = 1.0f / fmaxf(s, 1e-8f);
  }
  __syncthreads();

  // ---- B: waves 0-1 mask GEMM f32 (reg-held), waves 2-3 score GEMM f16 ----
  float macc[4][4];
  int x0 = 0, y0 = 0;
  if (tid < 128) {
    float msl = 0.0f;
    if (tid < 125) {
      int yg = tid / 25;
      int xg = tid - yg*25;
      y0 = yg*4; x0 = xg*4;
      #pragma unroll
      for (int i = 0; i < 4; ++i)
        #pragma unroll
        for (int j = 0; j < 4; ++j) macc[i][j] = 0.0f;
      for (int n = 0; n < NP; ++n) {
        float4 exv = *(float4*)&ex[n*100 + x0];
        float4 eyv = *(float4*)&eyt[n*20 + y0];
        macc[0][0] += eyv.x*exv.x; macc[0][1] += eyv.x*exv.y; macc[0][2] += eyv.x*exv.z; macc[0][3] += eyv.x*exv.w;
        macc[1][0] += eyv.y*exv.x; macc[1][1] += eyv.y*exv.y; macc[1][2] += eyv.y*exv.z; macc[1][3] += eyv.y*exv.w;
        macc[2][0] += eyv.z*exv.x; macc[2][1] += eyv.z*exv.y; macc[2][2] += eyv.z*exv.z; macc[2][3] += eyv.z*exv.w;
        macc[3][0] += eyv.w*exv.x; macc[3][1] += eyv.w*exv.y; macc[3][2] += eyv.w*exv.z; macc[3][3] += eyv.w*exv.w;
      }
      #pragma unroll
      for (int i = 0; i < 4; ++i)
        #pragma unroll
        for (int j = 0; j < 4; ++j) {
          float v = fminf(macc[i][j], 1.0f);
          macc[i][j] = v;
          msl += v;
        }
    }
    #pragma unroll
    for (int off = 32; off > 0; off >>= 1) msl += __shfl_down(msl, off);
    if ((tid & 63) == 0) red[tid >> 6] = msl;
  } else {
    int st = tid - 128;
    int ng = st >> 3;
    int xt = st & 7;
    int n0 = ng * 4;
    uint4 ea[4], eb4[4]; uint2 ec[4];
    #pragma unroll
    for (int i = 0; i < 4; ++i) {
      const unsigned int* p = &eyy[(n0 + i)*12];
      ea[i]  = *(const uint4*)p;
      eb4[i] = *(const uint4*)(p + 4);
      ec[i]  = *(const uint2*)(p + 8);
    }
    float sacc[4] = {0.0f, 0.0f, 0.0f, 0.0f};
    for (int x = xt; x < 100; x += 8) {
      const unsigned int* q = &Mp[x*12];
      uint4 ma = *(const uint4*)q;
      uint4 mb = *(const uint4*)(q + 4);
      uint2 mc = *(const uint2*)(q + 8);
      float cvx = cinv[x];
      #pragma unroll
      for (int i = 0; i < 4; ++i) {
        float t = 0.0f;
        t = fdot2f(ea[i].x, ma.x, t);  t = fdot2f(ea[i].y, ma.y, t);
        t = fdot2f(ea[i].z, ma.z, t);  t = fdot2f(ea[i].w, ma.w, t);
        t = fdot2f(eb4[i].x, mb.x, t); t = fdot2f(eb4[i].y, mb.y, t);
        t = fdot2f(eb4[i].z, mb.z, t); t = fdot2f(eb4[i].w, mb.w, t);
        t = fdot2f(ec[i].x, mc.x, t);  t = fdot2f(ec[i].y, mc.y, t);
        sacc[i] += t * ex[(n0 + i)*100 + x] * cvx;
      }
    }
    #pragma unroll
    for (int off = 4; off > 0; off >>= 1) {
      #pragma unroll
      for (int i = 0; i < 4; ++i) sacc[i] += __shfl_down(sacc[i], off, 8);
    }
    if (xt == 0) {
      #pragma unroll
      for (int i = 0; i < 4; ++i) ws_scr[blk*NP + n0 + i] = sacc[i];
    }
  }
  __syncthreads();                    // red[0..1] ready, ws_scr stores drained
  if (tid == 0) ws_msum[blk] = red[0] + red[1];

  // ---- per-image / per-batch counter sync (separate cachelines) ----
  __threadfence();                    // write back block's stores to device scope
  __syncthreads();
  if (tid == 0) {
    atomicAdd(&cnt[img*16], 1u);      // device-scope by default
    atomicAdd(&cnt[512 + bat*16], 1u);
    while (agentLoadU(&cnt[img*16]) < 20u)
      __builtin_amdgcn_s_sleep(4);
  }
  __syncthreads();

  // ---- normalized mask write from registers (single out write) ----
  if (tid == 0) {
    float s = 0.0f;
    for (int i = 0; i < SPI; ++i) s += agentLoadF(&ws_msum[img*SPI + i]);
    red[0] = 1.0f / fmaxf(s, 1e-8f);
  }
  __syncthreads();
  {
    const float inv = red[0];
    if (tid < 125) {
      float* ob = out + img*NPIX;
      #pragma unroll
      for (int i = 0; i < 4; ++i) {
        float4 v;
        v.x = macc[i][0] * inv;
        v.y = macc[i][1] * inv;
        v.z = macc[i][2] * inv;
        v.w = macc[i][3] * inv;
        *(float4*)&ob[(ys0 + y0 + i)*H + xb + x0] = v;
      }
    }
  }

  // ---- score finalize: one designated block per batch ----
  if (blk == bat*60) {
    if (tid == 0) {
      while (agentLoadU(&cnt[512 + bat*16]) < 60u)
        __builtin_amdgcn_s_sleep(4);
    }
    __syncthreads();
    if (tid < NP) {
      float s = 0.0f;
      for (int j = 0; j < 60; ++j)
        s += agentLoadF(&ws_scr[(bat*60 + j)*NP + tid]);
      out[NIMG*NPIX + bat*NP + tid] = s * (1.0f/3.0f);
    }
  }
}

extern "C" void kernel_launch(void* const* d_in, const int* in_sizes, int n_in,
                              void* d_out, int out_size, void* d_ws, size_t ws_size,
                              hipStream_t stream) {
  const float* cam   = (const float*)d_in[0];
  const float* cloud = (const float*)d_in[1];
  const float* mt    = (const float*)d_in[2];
  const float* blur  = (const float*)d_in[3];
  const float* b3    = (const float*)d_in[4];
  const float* b2    = (const float*)d_in[5];
  float* out = (float*)d_out;

  unsigned int* cnt = (unsigned int*)d_ws;          // [1024] u32 (4 KB)
  float* ws_msum = (float*)d_ws + 1024;             // [512]
  float* ws_scr  = (float*)d_ws + 1536;             // [480][64]

  hipMemsetAsync(cnt, 0, 4096, stream);             // reset counters each replay
  prs_all<<<NWORK, 256, 0, stream>>>(cam, cloud, mt, blur, b3, b2,
                                     out, cnt, ws_msum, ws_scr);
}